// Round 1
// baseline (232.387 us; speedup 1.0000x reference)
//
#include <hip/hip_runtime.h>
#include <hip/hip_bf16.h>

#define S_TOT 32768
#define C_IN 192
#define NB 2
#define NH 8
#define DH 64
#define ATT_SCALE 0.125f
#define NSLICE 128
#define GR_CH 8
#define GR_BK 32

// ---------------- workspace layout (float units) ----------------
#define G_OFF   0
#define G_SZ    (NB * C_IN * C_IN)
#define T_OFF   (G_OFF + G_SZ)
#define T_SZ    (NB * 512 * C_IN)
#define M_OFF   (T_OFF + T_SZ)
#define M_SZ    (NB * 512 * C_IN)
#define WBF_OFF (M_OFF + M_SZ)
#define WBF_SZ  (NB * C_IN * C_IN / 2)
#define P_OFF   (WBF_OFF + WBF_SZ)
#define P_SZ    (NB * NSLICE * C_IN * C_IN)

// split-weight / split-G / split-Z storage (each array = N ushorts = N/2 floats)
#define WEL      (512 * C_IN)          // 98304 elements per weight matrix
#define SPL_FL   (WEL / 2)             // 49152 floats per ushort array
#define WQH_OFF  (P_OFF + P_SZ)
#define WQM_OFF  (WQH_OFF + SPL_FL)
#define WQL_OFF  (WQM_OFF + SPL_FL)
#define WKH_OFF  (WQL_OFF + SPL_FL)
#define WKM_OFF  (WKH_OFF + SPL_FL)
#define WKL_OFF  (WKM_OFF + SPL_FL)
#define WOH_OFF  (WKL_OFF + SPL_FL)
#define WOL_OFF  (WOH_OFF + SPL_FL)
#define WVTH_OFF (WOL_OFF + SPL_FL)
#define WVTL_OFF (WVTH_OFF + SPL_FL)
#define GEL      (C_IN * C_IN)
#define GH_OFF   (WVTL_OFF + SPL_FL)
#define GM_OFF   (GH_OFF + NB * GEL / 2)
#define GL_OFF   (GM_OFF + NB * GEL / 2)
#define ZEL      (C_IN * 512)
#define ZH_OFF   (GL_OFF + NB * GEL / 2)
#define ZL_OFF   (ZH_OFF + NB * ZEL / 2)
#define WS_END   (ZL_OFF + NB * ZEL / 2)

typedef __attribute__((ext_vector_type(8))) short short8;
typedef __attribute__((ext_vector_type(4))) float f32x4;

__device__ inline unsigned short f2bf(float f) {   // RNE
    unsigned int u = __float_as_uint(f);
    u += 0x7fffu + ((u >> 16) & 1u);
    return (unsigned short)(u >> 16);
}

__device__ inline unsigned int pk_bf16(float a, float b) {  // packed RNE pair
    __hip_bfloat162 t = __float22bfloat162_rn(make_float2(a, b));
    unsigned int bits;
    __builtin_memcpy(&bits, &t, 4);
    return bits;
}

// x = hi + lo: hi = truncated bf16, lo = RNE bf16 of remainder -> ~2^-17 |x| residual
__device__ inline void split_bf(float v, unsigned short& h, unsigned short& l) {
    unsigned int u = __float_as_uint(v);
    h = (unsigned short)(u >> 16);
    float hf = __uint_as_float(u & 0xffff0000u);
    l = f2bf(v - hf);
}

// x = hi + mid + lo: ~2^-25 |x| residual (enough to feed softmax logits)
__device__ inline void split3_bf(float v, unsigned short& h, unsigned short& m, unsigned short& l) {
    unsigned int u = __float_as_uint(v);
    h = (unsigned short)(u >> 16);
    float hf = __uint_as_float(u & 0xffff0000u);
    float r1 = v - hf;
    unsigned int u1 = __float_as_uint(r1);
    m = (unsigned short)(u1 >> 16);
    float mf = __uint_as_float(u1 & 0xffff0000u);
    l = f2bf(r1 - mf);
}

__device__ inline unsigned long long pack4(const unsigned short* s) {
    return (unsigned long long)s[0] | ((unsigned long long)s[1] << 16)
         | ((unsigned long long)s[2] << 32) | ((unsigned long long)s[3] << 48);
}

// One unit of weight pre-splitting; 98304 units total spread over gram_partial's
// 256 blocks x 384 lanes. Regions: 0=wq(triple) 1=wk(triple) 2=wo(double) 3=wv^T(double).
__device__ inline void split_unit(int u, const float* wq, const float* wk,
                                  const float* wv, const float* wo, float* ws) {
    int region = u / 24576;
    int r = u - region * 24576;
    if (region < 3) {
        const float* src = (region == 0) ? wq : (region == 1) ? wk : wo;
        int i = r * 4;
        float4 v = *(const float4*)(src + i);
        if (region < 2) {
            unsigned short h[4], m[4], l[4];
            split3_bf(v.x, h[0], m[0], l[0]);
            split3_bf(v.y, h[1], m[1], l[1]);
            split3_bf(v.z, h[2], m[2], l[2]);
            split3_bf(v.w, h[3], m[3], l[3]);
            int base = (region == 0) ? WQH_OFF : WKH_OFF;
            *(unsigned long long*)((unsigned short*)(ws + base) + i)              = pack4(h);
            *(unsigned long long*)((unsigned short*)(ws + base + SPL_FL) + i)     = pack4(m);
            *(unsigned long long*)((unsigned short*)(ws + base + 2 * SPL_FL) + i) = pack4(l);
        } else {
            unsigned short h[4], l[4];
            split_bf(v.x, h[0], l[0]);
            split_bf(v.y, h[1], l[1]);
            split_bf(v.z, h[2], l[2]);
            split_bf(v.w, h[3], l[3]);
            *(unsigned long long*)((unsigned short*)(ws + WOH_OFF) + i) = pack4(h);
            *(unsigned long long*)((unsigned short*)(ws + WOL_OFF) + i) = pack4(l);
        }
    } else {
        // wv [512][192] -> WvT [192][512] split; consecutive u -> consecutive c (coalesced reads)
        int j4 = r / 192;
        int c  = r - j4 * 192;
        int j  = j4 * 4;
        unsigned short h[4], l[4];
#pragma unroll
        for (int jj = 0; jj < 4; ++jj)
            split_bf(wv[(size_t)(j + jj) * C_IN + c], h[jj], l[jj]);
        *(unsigned long long*)((unsigned short*)(ws + WVTH_OFF) + c * 512 + j) = pack4(h);
        *(unsigned long long*)((unsigned short*)(ws + WVTL_OFF) + c * 512 + j) = pack4(l);
    }
}

// ---------------- Gram via split-bf16 MFMA: P[b][slice] = X-slice * X-slice^T ----------------
// grid (128, NB), block 512 (8 waves). Spare lanes (tid<384) also pre-split the weights.
__global__ __launch_bounds__(512, 2) void gram_partial(const float* __restrict__ x,
                                                       const float* __restrict__ wq,
                                                       const float* __restrict__ wk,
                                                       const float* __restrict__ wv,
                                                       const float* __restrict__ wo,
                                                       float* __restrict__ ws) {
    int b     = blockIdx.y;
    int slice = blockIdx.x;
    int kbase = slice * (GR_CH * GR_BK);

    __shared__ unsigned short Hs[192 * 40];
    __shared__ unsigned short Lo[192 * 40];

    int tid  = threadIdx.x;
    int wave = tid >> 6;
    int lane = tid & 63;
    int rw   = wave & 3;          // row-tile group: rows 48*rw .. +47
    int cw   = wave >> 2;         // col-tile group: cols 96*cw .. +95
    int lm   = lane & 15, quad = lane >> 4;

    const float* xb = x + (size_t)b * C_IN * S_TOT;

    int lc[3], lkq[3];
#pragma unroll
    for (int q = 0; q < 3; q++) { int id = tid + 512 * q; lc[q] = id >> 3; lkq[q] = id & 7; }

    f32x4 acc[3][6];
#pragma unroll
    for (int mt = 0; mt < 3; mt++)
#pragma unroll
        for (int nt = 0; nt < 6; nt++) acc[mt][nt] = (f32x4){0.f, 0.f, 0.f, 0.f};

    float4 pf[3];
#pragma unroll
    for (int q = 0; q < 3; q++)
        pf[q] = *(const float4*)(xb + (size_t)lc[q] * S_TOT + kbase + lkq[q] * 4);

    // weight pre-split folded into spare lanes (distinct units per block, no sync needed)
    if (tid < 384) split_unit((b * NSLICE + slice) * 384 + tid, wq, wk, wv, wo, ws);

    for (int ch = 0; ch < GR_CH; ++ch) {
        __syncthreads();
#pragma unroll
        for (int q = 0; q < 3; q++) {
            unsigned short h[4], l[4];
            split_bf(pf[q].x, h[0], l[0]);
            split_bf(pf[q].y, h[1], l[1]);
            split_bf(pf[q].z, h[2], l[2]);
            split_bf(pf[q].w, h[3], l[3]);
            *(unsigned long long*)&Hs[lc[q] * 40 + lkq[q] * 4] = pack4(h);
            *(unsigned long long*)&Lo[lc[q] * 40 + lkq[q] * 4] = pack4(l);
        }
        __syncthreads();
        if (ch + 1 < GR_CH) {
            int k0 = kbase + (ch + 1) * GR_BK;
#pragma unroll
            for (int q = 0; q < 3; q++)
                pf[q] = *(const float4*)(xb + (size_t)lc[q] * S_TOT + k0 + lkq[q] * 4);
        }

        short8 ah[3], al[3];
#pragma unroll
        for (int mt = 0; mt < 3; mt++) {
            int row = 48 * rw + mt * 16 + lm;
            ah[mt] = *(const short8*)&Hs[row * 40 + quad * 8];
            al[mt] = *(const short8*)&Lo[row * 40 + quad * 8];
        }
#pragma unroll
        for (int nt = 0; nt < 6; nt++) {
            int col = 96 * cw + nt * 16 + lm;
            short8 bh = *(const short8*)&Hs[col * 40 + quad * 8];
            short8 bl = *(const short8*)&Lo[col * 40 + quad * 8];
#pragma unroll
            for (int mt = 0; mt < 3; mt++) {
                acc[mt][nt] = __builtin_amdgcn_mfma_f32_16x16x32_bf16(ah[mt], bh, acc[mt][nt], 0, 0, 0);
                acc[mt][nt] = __builtin_amdgcn_mfma_f32_16x16x32_bf16(ah[mt], bl, acc[mt][nt], 0, 0, 0);
                acc[mt][nt] = __builtin_amdgcn_mfma_f32_16x16x32_bf16(al[mt], bh, acc[mt][nt], 0, 0, 0);
            }
        }
    }

    float* Pb = ws + P_OFF + ((size_t)(b * NSLICE + slice)) * (C_IN * C_IN);
#pragma unroll
    for (int mt = 0; mt < 3; mt++) {
#pragma unroll
        for (int r = 0; r < 4; r++) {
            int row = 48 * rw + mt * 16 + quad * 4 + r;
#pragma unroll
            for (int nt = 0; nt < 6; nt++)
                Pb[row * C_IN + 96 * cw + nt * 16 + lm] = acc[mt][nt][r];
        }
    }
}

// ---------------- Gram reduce: single pass over all slices, emits triple-split G ----------------
// grid (144, NB), block 64 (1 wave): 288 waves, no atomics, no memset.
__global__ __launch_bounds__(64) void gram_reduce(float* __restrict__ ws) {
    int b = blockIdx.y;
    int idx4 = (blockIdx.x * 64 + threadIdx.x) * 4;
    const float* Pb = ws + P_OFF + (size_t)(b * NSLICE) * GEL + idx4;
    float4 acc = {0.f, 0.f, 0.f, 0.f};
#pragma unroll 8
    for (int s = 0; s < NSLICE; ++s) {
        float4 v = *(const float4*)(Pb + (size_t)s * GEL);
        acc.x += v.x; acc.y += v.y; acc.z += v.z; acc.w += v.w;
    }
    unsigned short h[4], m[4], l[4];
    split3_bf(acc.x, h[0], m[0], l[0]);
    split3_bf(acc.y, h[1], m[1], l[1]);
    split3_bf(acc.z, h[2], m[2], l[2]);
    split3_bf(acc.w, h[3], m[3], l[3]);
    *(unsigned long long*)((unsigned short*)(ws + GH_OFF) + (size_t)b * GEL + idx4) = pack4(h);
    *(unsigned long long*)((unsigned short*)(ws + GM_OFF) + (size_t)b * GEL + idx4) = pack4(m);
    *(unsigned long long*)((unsigned short*)(ws + GL_OFF) + (size_t)b * GEL + idx4) = pack4(l);
}

// ---------------- fused middle: Q = Wq_h*G -> sim -> softmax -> Z_h = Wo_h*attn ----------------
// grid (NB, NH), block 256 (4 waves). Triple-split MFMA on the softmax-feeding GEMMs
// (6 terms ~ fp32), double-split after softmax (error << final bf16-W rounding).
__global__ __launch_bounds__(256) void mid_kernel(float* __restrict__ ws) {
    int b = blockIdx.x, h = blockIdx.y;
    int tid  = threadIdx.x;
    int wave = tid >> 6;
    int lane = tid & 63;
    int lm = lane & 15, quad = lane >> 4;

    __shared__ float SQ[64 * 196];   // Q fp32 [64][196]; later reused as attn^T [64][68]

    const unsigned short* WQHp = (const unsigned short*)(ws + WQH_OFF);
    const unsigned short* WQMp = (const unsigned short*)(ws + WQM_OFF);
    const unsigned short* WQLp = (const unsigned short*)(ws + WQL_OFF);
    const unsigned short* WKHp = (const unsigned short*)(ws + WKH_OFF);
    const unsigned short* WKMp = (const unsigned short*)(ws + WKM_OFF);
    const unsigned short* WKLp = (const unsigned short*)(ws + WKL_OFF);
    const unsigned short* WOHp = (const unsigned short*)(ws + WOH_OFF);
    const unsigned short* WOLp = (const unsigned short*)(ws + WOL_OFF);
    const unsigned short* GHb  = (const unsigned short*)(ws + GH_OFF) + (size_t)b * GEL;
    const unsigned short* GMb  = (const unsigned short*)(ws + GM_OFF) + (size_t)b * GEL;
    const unsigned short* GLb  = (const unsigned short*)(ws + GL_OFF) + (size_t)b * GEL;

    // ---- Q = Wq_h * G (64x192), G symmetric so B-frags = G rows ----
    f32x4 qacc[12];
#pragma unroll
    for (int ct = 0; ct < 12; ++ct) qacc[ct] = (f32x4){0.f, 0.f, 0.f, 0.f};

    int qr = (h * 64 + wave * 16 + lm) * C_IN;
    for (int ch = 0; ch < 6; ++ch) {
        int k0 = ch * 32 + quad * 8;
        short8 aH = *(const short8*)(WQHp + qr + k0);
        short8 aM = *(const short8*)(WQMp + qr + k0);
        short8 aL = *(const short8*)(WQLp + qr + k0);
#pragma unroll
        for (int ct = 0; ct < 12; ++ct) {
            int gr = (ct * 16 + lm) * C_IN + k0;
            short8 bH = *(const short8*)(GHb + gr);
            short8 bM = *(const short8*)(GMb + gr);
            short8 bL = *(const short8*)(GLb + gr);
            qacc[ct] = __builtin_amdgcn_mfma_f32_16x16x32_bf16(aH, bH, qacc[ct], 0, 0, 0);
            qacc[ct] = __builtin_amdgcn_mfma_f32_16x16x32_bf16(aH, bM, qacc[ct], 0, 0, 0);
            qacc[ct] = __builtin_amdgcn_mfma_f32_16x16x32_bf16(aM, bH, qacc[ct], 0, 0, 0);
            qacc[ct] = __builtin_amdgcn_mfma_f32_16x16x32_bf16(aH, bL, qacc[ct], 0, 0, 0);
            qacc[ct] = __builtin_amdgcn_mfma_f32_16x16x32_bf16(aM, bM, qacc[ct], 0, 0, 0);
            qacc[ct] = __builtin_amdgcn_mfma_f32_16x16x32_bf16(aL, bH, qacc[ct], 0, 0, 0);
        }
    }
#pragma unroll
    for (int ct = 0; ct < 12; ++ct)
#pragma unroll
        for (int r = 0; r < 4; ++r)
            SQ[(wave * 16 + quad * 4 + r) * 196 + ct * 16 + lm] = qacc[ct][r];
    __syncthreads();

    // ---- sim = Q * Wk_h^T (64x64), Q triple-split on read ----
    f32x4 sacc[4];
#pragma unroll
    for (int ct = 0; ct < 4; ++ct) sacc[ct] = (f32x4){0.f, 0.f, 0.f, 0.f};
    for (int ch = 0; ch < 6; ++ch) {
        int k0 = ch * 32 + quad * 8;
        float qv[8];
        *(float4*)&qv[0] = *(const float4*)&SQ[(wave * 16 + lm) * 196 + k0];
        *(float4*)&qv[4] = *(const float4*)&SQ[(wave * 16 + lm) * 196 + k0 + 4];
        short8 aH, aM, aL;
#pragma unroll
        for (int j = 0; j < 8; ++j) {
            unsigned short hh, mm, ll;
            split3_bf(qv[j], hh, mm, ll);
            aH[j] = (short)hh; aM[j] = (short)mm; aL[j] = (short)ll;
        }
#pragma unroll
        for (int ct = 0; ct < 4; ++ct) {
            int kr = (h * 64 + ct * 16 + lm) * C_IN + k0;
            short8 bH = *(const short8*)(WKHp + kr);
            short8 bM = *(const short8*)(WKMp + kr);
            short8 bL = *(const short8*)(WKLp + kr);
            sacc[ct] = __builtin_amdgcn_mfma_f32_16x16x32_bf16(aH, bH, sacc[ct], 0, 0, 0);
            sacc[ct] = __builtin_amdgcn_mfma_f32_16x16x32_bf16(aH, bM, sacc[ct], 0, 0, 0);
            sacc[ct] = __builtin_amdgcn_mfma_f32_16x16x32_bf16(aM, bH, sacc[ct], 0, 0, 0);
            sacc[ct] = __builtin_amdgcn_mfma_f32_16x16x32_bf16(aH, bL, sacc[ct], 0, 0, 0);
            sacc[ct] = __builtin_amdgcn_mfma_f32_16x16x32_bf16(aM, bM, sacc[ct], 0, 0, 0);
            sacc[ct] = __builtin_amdgcn_mfma_f32_16x16x32_bf16(aL, bH, sacc[ct], 0, 0, 0);
        }
    }
    __syncthreads();   // all Q reads done before attn^T overwrites SQ

    // ---- softmax over j (cols), store attn^T into At[j][i] ----
    float* At = SQ;    // [64][68]
#pragma unroll
    for (int r = 0; r < 4; ++r) {
        float s0 = sacc[0][r] * ATT_SCALE;
        float s1 = sacc[1][r] * ATT_SCALE;
        float s2 = sacc[2][r] * ATT_SCALE;
        float s3 = sacc[3][r] * ATT_SCALE;
        float mx = fmaxf(fmaxf(s0, s1), fmaxf(s2, s3));
        mx = fmaxf(mx, __shfl_xor(mx, 1));
        mx = fmaxf(mx, __shfl_xor(mx, 2));
        mx = fmaxf(mx, __shfl_xor(mx, 4));
        mx = fmaxf(mx, __shfl_xor(mx, 8));
        float e0 = __expf(s0 - mx), e1 = __expf(s1 - mx);
        float e2 = __expf(s2 - mx), e3 = __expf(s3 - mx);
        float sum = (e0 + e1) + (e2 + e3);
        sum += __shfl_xor(sum, 1);
        sum += __shfl_xor(sum, 2);
        sum += __shfl_xor(sum, 4);
        sum += __shfl_xor(sum, 8);
        float inv = 1.0f / sum;
        int i = wave * 16 + quad * 4 + r;
        At[lm * 68 + i]        = e0 * inv;
        At[(16 + lm) * 68 + i] = e1 * inv;
        At[(32 + lm) * 68 + i] = e2 * inv;
        At[(48 + lm) * 68 + i] = e3 * inv;
    }
    __syncthreads();

    // ---- Z_h = Wo[:, 64h:64h+64] * attn (192x64), double-split ----
    f32x4 zacc[3][4];
#pragma unroll
    for (int mt = 0; mt < 3; ++mt)
#pragma unroll
        for (int ct = 0; ct < 4; ++ct) zacc[mt][ct] = (f32x4){0.f, 0.f, 0.f, 0.f};

    for (int ch = 0; ch < 2; ++ch) {
        int k0 = ch * 32 + quad * 8;
        short8 bH[4], bL[4];
#pragma unroll
        for (int ct = 0; ct < 4; ++ct) {
            float av[8];
            *(float4*)&av[0] = *(const float4*)&At[(ct * 16 + lm) * 68 + k0];
            *(float4*)&av[4] = *(const float4*)&At[(ct * 16 + lm) * 68 + k0 + 4];
#pragma unroll
            for (int j = 0; j < 8; ++j) {
                unsigned short hh, ll;
                split_bf(av[j], hh, ll);
                bH[ct][j] = (short)hh; bL[ct][j] = (short)ll;
            }
        }
#pragma unroll
        for (int mt = 0; mt < 3; ++mt) {
            int orow = (wave * 48 + mt * 16 + lm) * 512 + h * 64 + k0;
            short8 aH = *(const short8*)(WOHp + orow);
            short8 aL = *(const short8*)(WOLp + orow);
#pragma unroll
            for (int ct = 0; ct < 4; ++ct) {
                zacc[mt][ct] = __builtin_amdgcn_mfma_f32_16x16x32_bf16(aH, bH[ct], zacc[mt][ct], 0, 0, 0);
                zacc[mt][ct] = __builtin_amdgcn_mfma_f32_16x16x32_bf16(aH, bL[ct], zacc[mt][ct], 0, 0, 0);
                zacc[mt][ct] = __builtin_amdgcn_mfma_f32_16x16x32_bf16(aL, bH[ct], zacc[mt][ct], 0, 0, 0);
            }
        }
    }

    unsigned short* ZHb = (unsigned short*)(ws + ZH_OFF) + (size_t)b * ZEL;
    unsigned short* ZLb = (unsigned short*)(ws + ZL_OFF) + (size_t)b * ZEL;
#pragma unroll
    for (int mt = 0; mt < 3; ++mt)
#pragma unroll
        for (int r = 0; r < 4; ++r) {
            int o = wave * 48 + mt * 16 + quad * 4 + r;
#pragma unroll
            for (int ct = 0; ct < 4; ++ct) {
                unsigned short hh, ll;
                split_bf(zacc[mt][ct][r], hh, ll);
                int idx = o * 512 + h * 64 + ct * 16 + lm;
                ZHb[idx] = hh;
                ZLb[idx] = ll;
            }
        }
}

// ---------------- W = Z * Wv^T (192x192, K=512 => head-sum via K), bf16 packed out ----------------
// grid (NB, 2), block 512 (8 waves): pure-register MFMA, no LDS, no barriers.
__global__ __launch_bounds__(512) void wmix_kernel(float* __restrict__ ws) {
    int b = blockIdx.x, half = blockIdx.y;
    int tid  = threadIdx.x;
    int wave = tid >> 6, lane = tid & 63;
    int lm = lane & 15, quad = lane >> 4;
    int rw = wave & 3, cw = wave >> 2;

    const unsigned short* ZHb = (const unsigned short*)(ws + ZH_OFF) + (size_t)b * ZEL;
    const unsigned short* ZLb = (const unsigned short*)(ws + ZL_OFF) + (size_t)b * ZEL;
    const unsigned short* VTH = (const unsigned short*)(ws + WVTH_OFF);
    const unsigned short* VTL = (const unsigned short*)(ws + WVTL_OFF);

    f32x4 acc[3][3];
#pragma unroll
    for (int mt = 0; mt < 3; ++mt)
#pragma unroll
        for (int ct = 0; ct < 3; ++ct) acc[mt][ct] = (f32x4){0.f, 0.f, 0.f, 0.f};

    for (int ch = 0; ch < 16; ++ch) {
        int k0 = ch * 32 + quad * 8;
        short8 aH[3], aL[3];
#pragma unroll
        for (int mt = 0; mt < 3; ++mt) {
            int o = (rw * 48 + mt * 16 + lm) * 512 + k0;
            aH[mt] = *(const short8*)(ZHb + o);
            aL[mt] = *(const short8*)(ZLb + o);
        }
#pragma unroll
        for (int ct = 0; ct < 3; ++ct) {
            int c = (half * 96 + cw * 48 + ct * 16 + lm) * 512 + k0;
            short8 bH = *(const short8*)(VTH + c);
            short8 bL = *(const short8*)(VTL + c);
#pragma unroll
            for (int mt = 0; mt < 3; ++mt) {
                acc[mt][ct] = __builtin_amdgcn_mfma_f32_16x16x32_bf16(aH[mt], bH, acc[mt][ct], 0, 0, 0);
                acc[mt][ct] = __builtin_amdgcn_mfma_f32_16x16x32_bf16(aH[mt], bL, acc[mt][ct], 0, 0, 0);
                acc[mt][ct] = __builtin_amdgcn_mfma_f32_16x16x32_bf16(aL[mt], bH, acc[mt][ct], 0, 0, 0);
            }
        }
    }

    unsigned short* Wb = (unsigned short*)(ws + WBF_OFF) + (size_t)b * C_IN * C_IN;
#pragma unroll
    for (int mt = 0; mt < 3; ++mt)
#pragma unroll
        for (int r = 0; r < 4; ++r) {
            int m = rw * 48 + mt * 16 + quad * 4 + r;
#pragma unroll
            for (int ct = 0; ct < 3; ++ct)
                Wb[m * C_IN + half * 96 + cw * 48 + ct * 16 + lm] = f2bf(acc[mt][ct][r]);
        }
}

// ---------------- Gram fallback (fp32 atomic; used only if ws too small) ----------------
__global__ __launch_bounds__(512, 2) void gram_atomic(const float* __restrict__ x,
                                                      float* __restrict__ G) {
    int b     = blockIdx.y;
    int kbase = blockIdx.x * (GR_CH * GR_BK);

    __shared__ float Ls[GR_BK][196];

    int tid = threadIdx.x;
    int tx  = tid & 15;
    int tyy = tid >> 4;

    const float* xb = x + (size_t)b * C_IN * S_TOT;

    int lc[3], lkq[3];
#pragma unroll
    for (int q = 0; q < 3; q++) { int id = tid + 512 * q; lc[q] = id >> 3; lkq[q] = id & 7; }

    float acc[6][12] = {};
    float4 pf[3];

#pragma unroll
    for (int q = 0; q < 3; q++)
        pf[q] = *(const float4*)(xb + (size_t)lc[q] * S_TOT + kbase + lkq[q] * 4);

    for (int ch = 0; ch < GR_CH; ++ch) {
        __syncthreads();
#pragma unroll
        for (int q = 0; q < 3; q++) {
            Ls[lkq[q] * 4 + 0][lc[q]] = pf[q].x;
            Ls[lkq[q] * 4 + 1][lc[q]] = pf[q].y;
            Ls[lkq[q] * 4 + 2][lc[q]] = pf[q].z;
            Ls[lkq[q] * 4 + 3][lc[q]] = pf[q].w;
        }
        __syncthreads();
        if (ch + 1 < GR_CH) {
            int k0 = kbase + (ch + 1) * GR_BK;
#pragma unroll
            for (int q = 0; q < 3; q++)
                pf[q] = *(const float4*)(xb + (size_t)lc[q] * S_TOT + k0 + lkq[q] * 4);
        }
#pragma unroll
        for (int kk = 0; kk < GR_BK; ++kk) {
            float a[6], bb[12];
#pragma unroll
            for (int rr = 0; rr < 6; ++rr)  a[rr] = Ls[kk][tyy + 32 * rr];
#pragma unroll
            for (int cc = 0; cc < 12; ++cc) bb[cc] = Ls[kk][tx + 16 * cc];
#pragma unroll
            for (int rr = 0; rr < 6; ++rr)
#pragma unroll
                for (int cc = 0; cc < 12; ++cc)
                    acc[rr][cc] = fmaf(a[rr], bb[cc], acc[rr][cc]);
        }
    }

    float* Gb = G + b * C_IN * C_IN;
#pragma unroll
    for (int rr = 0; rr < 6; ++rr)
#pragma unroll
        for (int cc = 0; cc < 12; ++cc)
            atomicAdd(&Gb[(tyy + 32 * rr) * C_IN + tx + 16 * cc], acc[rr][cc]);
}

// ---------------- generic 64x64-tile GEMM (fp32 out; fallback path) ----------------
__global__ __launch_bounds__(256) void gemm64_kernel(const float* __restrict__ A,
                                                     const float* __restrict__ B,
                                                     float* __restrict__ C,
                                                     int K, int N,
                                                     long aStride, long bStride, long cStride) {
    int mi0 = blockIdx.x * 64;
    int nj0 = blockIdx.y * 64;
    int b   = blockIdx.z;

    __shared__ float As[16][68];
    __shared__ float Bs[16][68];

    int tid = threadIdx.x;
    int tx = tid & 15, ty = tid >> 4;
    int lrow = tid >> 2, lk = (tid & 3) * 4;
    int ldk = tid >> 4, ldn = (tid & 15) * 4;

    const float* Ab = A + b * aStride;
    const float* Bb = B + b * bStride;

    float acc[4][4] = {};

    for (int k0 = 0; k0 < K; k0 += 16) {
        float4 av = *(const float4*)(Ab + (size_t)(mi0 + lrow) * K + k0 + lk);
        float4 bv = *(const float4*)(Bb + (size_t)(k0 + ldk) * N + nj0 + ldn);
        __syncthreads();
        As[lk + 0][lrow] = av.x; As[lk + 1][lrow] = av.y;
        As[lk + 2][lrow] = av.z; As[lk + 3][lrow] = av.w;
        *(float4*)&Bs[ldk][ldn] = bv;
        __syncthreads();
#pragma unroll
        for (int kk = 0; kk < 16; kk++) {
            float4 a = *(const float4*)&As[kk][ty * 4];
            float4 bb = *(const float4*)&Bs[kk][tx * 4];
            acc[0][0] += a.x * bb.x; acc[0][1] += a.x * bb.y; acc[0][2] += a.x * bb.z; acc[0][3] += a.x * bb.w;
            acc[1][0] += a.y * bb.x; acc[1][1] += a.y * bb.y; acc[1][2] += a.y * bb.z; acc[1][3] += a.y * bb.w;
            acc[2][0] += a.z * bb.x; acc[2][1] += a.z * bb.y; acc[2][2] += a.z * bb.z; acc[2][3] += a.z * bb.w;
            acc[3][0] += a.w * bb.x; acc[3][1] += a.w * bb.y; acc[3][2] += a.w * bb.z; acc[3][3] += a.w * bb.w;
        }
    }

    float* Cb = C + b * cStride;
#pragma unroll
    for (int r = 0; r < 4; r++) {
        float4 v = { acc[r][0], acc[r][1], acc[r][2], acc[r][3] };
        *(float4*)(Cb + (size_t)(mi0 + ty * 4 + r) * N + nj0 + tx * 4) = v;
    }
}

// ---------------- same GEMM, bf16 packed output (fallback path) ----------------
__global__ __launch_bounds__(256) void gemm64bf_kernel(const float* __restrict__ A,
                                                       const float* __restrict__ B,
                                                       unsigned short* __restrict__ C,
                                                       int K, int N,
                                                       long aStride, long bStride, long cStride) {
    int mi0 = blockIdx.x * 64;
    int nj0 = blockIdx.y * 64;
    int b   = blockIdx.z;

    __shared__ float As[16][68];
    __shared__ float Bs[16][68];

    int tid = threadIdx.x;
    int tx = tid & 15, ty = tid >> 4;
    int lrow = tid >> 2, lk = (tid & 3) * 4;
    int ldk = tid >> 4, ldn = (tid & 15) * 4;

    const float* Ab = A + b * aStride;
    const float* Bb = B + b * bStride;

    float acc[4][4] = {};

    for (int k0 = 0; k0 < K; k0 += 16) {
        float4 av = *(const float4*)(Ab + (size_t)(mi0 + lrow) * K + k0 + lk);
        float4 bv = *(const float4*)(Bb + (size_t)(k0 + ldk) * N + nj0 + ldn);
        __syncthreads();
        As[lk + 0][lrow] = av.x; As[lk + 1][lrow] = av.y;
        As[lk + 2][lrow] = av.z; As[lk + 3][lrow] = av.w;
        *(float4*)&Bs[ldk][ldn] = bv;
        __syncthreads();
#pragma unroll
        for (int kk = 0; kk < 16; kk++) {
            float4 a = *(const float4*)&As[kk][ty * 4];
            float4 bb = *(const float4*)&Bs[kk][tx * 4];
            acc[0][0] += a.x * bb.x; acc[0][1] += a.x * bb.y; acc[0][2] += a.x * bb.z; acc[0][3] += a.x * bb.w;
            acc[1][0] += a.y * bb.x; acc[1][1] += a.y * bb.y; acc[1][2] += a.y * bb.z; acc[1][3] += a.y * bb.w;
            acc[2][0] += a.z * bb.x; acc[2][1] += a.z * bb.y; acc[2][2] += a.z * bb.z; acc[2][3] += a.z * bb.w;
            acc[3][0] += a.w * bb.x; acc[3][1] += a.w * bb.y; acc[3][2] += a.w * bb.z; acc[3][3] += a.w * bb.w;
        }
    }

    unsigned short* Cb = C + b * cStride;
#pragma unroll
    for (int r = 0; r < 4; r++) {
        union { unsigned long long q; unsigned int u[2]; } pk;
        pk.u[0] = pk_bf16(acc[r][0], acc[r][1]);
        pk.u[1] = pk_bf16(acc[r][2], acc[r][3]);
        *(unsigned long long*)&Cb[(size_t)(mi0 + ty * 4 + r) * N + nj0 + tx * 4] = pk.q;
    }
}

// ---------------- fallback fused sim/softmax/M ----------------
__global__ __launch_bounds__(256) void simsoftm_kernel(const float* __restrict__ T,
                                                       const float* __restrict__ wk,
                                                       const float* __restrict__ wv,
                                                       float* __restrict__ M) {
    int b = blockIdx.x, h = blockIdx.y;

    __shared__ float As[16][68];
    __shared__ float Bs[16][68];
    __shared__ float At[64][68];

    int tid = threadIdx.x;
    int tx = tid & 15, ty = tid >> 4;
    int ldk = tid >> 4, ldn = (tid & 15) * 4;
    int lrow = tid >> 2, lk = (tid & 3) * 4;

    const float* Th  = T + (size_t)b * 512 * C_IN + (size_t)(h * 64) * C_IN;
    const float* wkh = wk + (size_t)(h * 64) * C_IN;
    const float* wvh = wv + (size_t)(h * 64) * C_IN;

    float acc[4][4] = {};
    for (int k0 = 0; k0 < C_IN; k0 += 16) {
        float4 av = *(const float4*)(Th  + (size_t)lrow * C_IN + k0 + lk);
        float4 bv = *(const float4*)(wkh + (size_t)lrow * C_IN + k0 + lk);
        __syncthreads();
        As[lk + 0][lrow] = av.x; As[lk + 1][lrow] = av.y;
        As[lk + 2][lrow] = av.z; As[lk + 3][lrow] = av.w;
        Bs[lk + 0][lrow] = bv.x; Bs[lk + 1][lrow] = bv.y;
        Bs[lk + 2][lrow] = bv.z; Bs[lk + 3][lrow] = bv.w;
        __syncthreads();
#pragma unroll
        for (int kk = 0; kk < 16; kk++) {
            float4 a = *(const float4*)&As[kk][ty * 4];
            float4 bb = *(const float4*)&Bs[kk][tx * 4];
            acc[0][0] += a.x * bb.x; acc[0][1] += a.x * bb.y; acc[0][2] += a.x * bb.z; acc[0][3] += a.x * bb.w;
            acc[1][0] += a.y * bb.x; acc[1][1] += a.y * bb.y; acc[1][2] += a.y * bb.z; acc[1][3] += a.y * bb.w;
            acc[2][0] += a.z * bb.x; acc[2][1] += a.z * bb.y; acc[2][2] += a.z * bb.z; acc[2][3] += a.z * bb.w;
            acc[3][0] += a.w * bb.x; acc[3][1] += a.w * bb.y; acc[3][2] += a.w * bb.z; acc[3][3] += a.w * bb.w;
        }
    }

#pragma unroll
    for (int r = 0; r < 4; r++) {
        float s0 = acc[r][0] * ATT_SCALE, s1 = acc[r][1] * ATT_SCALE;
        float s2 = acc[r][2] * ATT_SCALE, s3 = acc[r][3] * ATT_SCALE;
        float mx = fmaxf(fmaxf(s0, s1), fmaxf(s2, s3));
        mx = fmaxf(mx, __shfl_xor(mx, 1));
        mx = fmaxf(mx, __shfl_xor(mx, 2));
        mx = fmaxf(mx, __shfl_xor(mx, 4));
        mx = fmaxf(mx, __shfl_xor(mx, 8));
        float e0 = __expf(s0 - mx), e1 = __expf(s1 - mx);
        float e2 = __expf(s2 - mx), e3 = __expf(s3 - mx);
        float sum = (e0 + e1) + (e2 + e3);
        sum += __shfl_xor(sum, 1);
        sum += __shfl_xor(sum, 2);
        sum += __shfl_xor(sum, 4);
        sum += __shfl_xor(sum, 8);
        float inv = 1.0f / sum;
        At[tx * 4 + 0][ty * 4 + r] = e0 * inv;
        At[tx * 4 + 1][ty * 4 + r] = e1 * inv;
        At[tx * 4 + 2][ty * 4 + r] = e2 * inv;
        At[tx * 4 + 3][ty * 4 + r] = e3 * inv;
    }

    float* Mb = M + (size_t)b * 512 * C_IN + (size_t)(h * 64) * C_IN;
    for (int nj = 0; nj < C_IN; nj += 64) {
        float acc2[4][4] = {};
        for (int j0 = 0; j0 < 64; j0 += 16) {
            float4 bv = *(const float4*)(wvh + (size_t)(j0 + ldk) * C_IN + nj + ldn);
            __syncthreads();
            *(float4*)&Bs[ldk][ldn] = bv;
            __syncthreads();
#pragma unroll
            for (int kk = 0; kk < 16; kk++) {
                float4 a = *(const float4*)&At[j0 + kk][ty * 4];
                float4 bb = *(const float4*)&Bs[kk][tx * 4];
                acc2[0][0] += a.x * bb.x; acc2[0][1] += a.x * bb.y; acc2[0][2] += a.x * bb.z; acc2[0][3] += a.x * bb.w;
                acc2[1][0] += a.y * bb.x; acc2[1][1] += a.y * bb.y; acc2[1][2] += a.y * bb.z; acc2[1][3] += a.y * bb.w;
                acc2[2][0] += a.z * bb.x; acc2[2][1] += a.z * bb.y; acc2[2][2] += a.z * bb.z; acc2[2][3] += a.z * bb.w;
                acc2[3][0] += a.w * bb.x; acc2[3][1] += a.w * bb.y; acc2[3][2] += a.w * bb.z; acc2[3][3] += a.w * bb.w;
            }
        }
#pragma unroll
        for (int r = 0; r < 4; r++) {
            float4 v = { acc2[r][0], acc2[r][1], acc2[r][2], acc2[r][3] };
            *(float4*)(Mb + (size_t)(ty * 4 + r) * C_IN + nj + tx * 4) = v;
        }
    }
}

// ---------------- out = W*x + bo, bf16 MFMA. grid (256, NB), block 256 (4 waves) ----------------
__global__ __launch_bounds__(256) void final_kernel(const float* __restrict__ x,
                                                    const unsigned short* __restrict__ Wbf,
                                                    const float* __restrict__ bo,
                                                    float* __restrict__ out) {
    int n0 = blockIdx.x * 128;
    int b  = blockIdx.y;

    __shared__ unsigned short Xs[128 * 40];

    int tid  = threadIdx.x;
    int wave = tid >> 6;
    int lane = tid & 63;
    int wm   = (wave & 1) * 96;
    int wn   = (wave >> 1) * 64;
    int lm   = lane & 15, quad = lane >> 4;

    int sn  = tid & 127;
    int skh = (tid >> 7) * 16;

    const float* xsrc = x + (size_t)b * C_IN * S_TOT + n0 + sn;
    const unsigned short* Wb = Wbf + b * C_IN * C_IN;

    f32x4 acc[6][4];
#pragma unroll
    for (int mt = 0; mt < 6; mt++)
#pragma unroll
        for (int nt = 0; nt < 4; nt++) acc[mt][nt] = (f32x4){0.f, 0.f, 0.f, 0.f};

    float pf[16];
#pragma unroll
    for (int j = 0; j < 16; j++) pf[j] = xsrc[(size_t)(skh + j) * S_TOT];

    for (int kc = 0; kc < 6; ++kc) {
        int k0 = kc * 32;
        __syncthreads();
        {
            union { uint4 q; unsigned int u[4]; } pk0, pk1;
#pragma unroll
            for (int j = 0; j < 4; j++) {
                pk0.u[j] = pk_bf16(pf[2 * j],     pf[2 * j + 1]);
                pk1.u[j] = pk_bf16(pf[8 + 2 * j], pf[8 + 2 * j + 1]);
            }
            *(uint4*)&Xs[sn * 40 + skh + 0] = pk0.q;
            *(uint4*)&Xs[sn * 40 + skh + 8] = pk1.q;
        }
        __syncthreads();
        if (kc + 1 < 6) {
            int kn = k0 + 32;
#pragma unroll
            for (int j = 0; j < 16; j++) pf[j] = xsrc[(size_t)(kn + skh + j) * S_TOT];
        }

        short8 afr[6];
#pragma unroll
        for (int mt = 0; mt < 6; mt++)
            afr[mt] = *(const short8*)(Wb + (size_t)(wm + mt * 16 + lm) * C_IN + k0 + quad * 8);
#pragma unroll
        for (int nt = 0; nt < 4; nt++) {
            short8 bfr = *(const short8*)&Xs[(wn + nt * 16 + lm) * 40 + quad * 8];
#pragma unroll
            for (int mt = 0; mt < 6; mt++)
                acc[mt][nt] = __builtin_amdgcn_mfma_f32_16x16x32_bf16(afr[mt], bfr, acc[mt][nt], 0, 0, 0);
        }
    }

#pragma unroll
    for (int mt = 0; mt < 6; mt++) {
#pragma unroll
        for (int r = 0; r < 4; r++) {
            int m = wm + mt * 16 + quad * 4 + r;
            float bias = bo[m];
            float* op = out + ((size_t)b * C_IN + m) * S_TOT + n0;
#pragma unroll
            for (int nt = 0; nt < 4; nt++)
                op[wn + nt * 16 + lm] = acc[mt][nt][r] + bias;
        }
    }
}

extern "C" void kernel_launch(void* const* d_in, const int* in_sizes, int n_in,
                              void* d_out, int out_size, void* d_ws, size_t ws_size,
                              hipStream_t stream) {
    const float* x  = (const float*)d_in[0];
    const float* wq = (const float*)d_in[1];
    const float* wk = (const float*)d_in[2];
    const float* wv = (const float*)d_in[3];
    const float* wo = (const float*)d_in[4];
    const float* bo = (const float*)d_in[5];
    float* out = (float*)d_out;
    float* ws  = (float*)d_ws;

    unsigned short* gWbf = (unsigned short*)(ws + WBF_OFF);

    bool bigws = ws_size >= (size_t)WS_END * sizeof(float);
    if (bigws) {
        // 5 dispatches: gram(+weight split) -> reduce(+G split) -> fused middle -> W-mix -> final
        gram_partial<<<dim3(NSLICE, NB), 512, 0, stream>>>(x, wq, wk, wv, wo, ws);
        gram_reduce<<<dim3(144, NB), 64, 0, stream>>>(ws);
        mid_kernel<<<dim3(NB, NH), 256, 0, stream>>>(ws);
        wmix_kernel<<<dim3(NB, 2), 512, 0, stream>>>(ws);
        final_kernel<<<dim3(256, NB), 256, 0, stream>>>(x, gWbf, bo, out);
    } else {
        // fallback: original proven chain
        float* gG = ws + G_OFF;
        float* gT = ws + T_OFF;
        float* gM = ws + M_OFF;
        hipMemsetAsync(gG, 0, G_SZ * sizeof(float), stream);
        gram_atomic<<<dim3(NSLICE, NB), 512, 0, stream>>>(x, gG);
        gemm64_kernel<<<dim3(8, 3, NB), 256, 0, stream>>>(
            wq, gG, gT, C_IN, C_IN, 0L, (long)(C_IN * C_IN), (long)(512 * C_IN));
        simsoftm_kernel<<<dim3(NB, NH), 256, 0, stream>>>(gT, wk, wv, gM);
        gemm64bf_kernel<<<dim3(3, 3, NB), 256, 0, stream>>>(
            wo, gM, gWbf, 512, C_IN, 0L, (long)(512 * C_IN), (long)(C_IN * C_IN));
        final_kernel<<<dim3(256, NB), 256, 0, stream>>>(x, gWbf, bo, out);
    }
}

// Round 2
// 227.146 us; speedup vs baseline: 1.0231x; 1.0231x over previous
//
#include <hip/hip_runtime.h>
#include <hip/hip_bf16.h>

#define S_TOT 32768
#define C_IN 192
#define NB 2
#define NH 8
#define DH 64
#define ATT_SCALE 0.125f
#define NSLICE 128
#define GR_CH 8
#define GR_BK 32

// ---------------- workspace layout (float units) ----------------
#define G_OFF   0
#define G_SZ    (NB * C_IN * C_IN)
#define T_OFF   (G_OFF + G_SZ)
#define T_SZ    (NB * 512 * C_IN)
#define M_OFF   (T_OFF + T_SZ)
#define M_SZ    (NB * 512 * C_IN)
#define WBF_OFF (M_OFF + M_SZ)
#define WBF_SZ  (NB * C_IN * C_IN / 2)
#define P_OFF   (WBF_OFF + WBF_SZ)
#define P_SZ    (NB * NSLICE * C_IN * C_IN)

// split-weight / split-G / split-Z storage (each array = N ushorts = N/2 floats)
#define WEL      (512 * C_IN)          // 98304 elements per weight matrix
#define SPL_FL   (WEL / 2)             // 49152 floats per ushort array
#define WQH_OFF  (P_OFF + P_SZ)
#define WQM_OFF  (WQH_OFF + SPL_FL)
#define WQL_OFF  (WQM_OFF + SPL_FL)
#define WKH_OFF  (WQL_OFF + SPL_FL)
#define WKM_OFF  (WKH_OFF + SPL_FL)
#define WKL_OFF  (WKM_OFF + SPL_FL)
#define WOH_OFF  (WKL_OFF + SPL_FL)
#define WOL_OFF  (WOH_OFF + SPL_FL)
#define WVTH_OFF (WOL_OFF + SPL_FL)
#define WVTL_OFF (WVTH_OFF + SPL_FL)
#define GEL      (C_IN * C_IN)
#define GH_OFF   (WVTL_OFF + SPL_FL)
#define GM_OFF   (GH_OFF + NB * GEL / 2)
#define GL_OFF   (GM_OFF + NB * GEL / 2)
#define ZEL      (C_IN * 512)
#define ZH_OFF   (GL_OFF + NB * GEL / 2)
#define ZL_OFF   (ZH_OFF + NB * ZEL / 2)
#define WS_END   (ZL_OFF + NB * ZEL / 2)

// Qt = Wq*G triple-split, aliased into the (dead after gram_reduce) P region
#define PT_EL    (512 * C_IN)
#define QTH_OFF  (P_OFF)
#define QTM_OFF  (QTH_OFF + NB * PT_EL / 2)
#define QTL_OFF  (QTM_OFF + NB * PT_EL / 2)

typedef __attribute__((ext_vector_type(8))) short short8;
typedef __attribute__((ext_vector_type(4))) float f32x4;

__device__ inline unsigned short f2bf(float f) {   // RNE
    unsigned int u = __float_as_uint(f);
    u += 0x7fffu + ((u >> 16) & 1u);
    return (unsigned short)(u >> 16);
}

__device__ inline unsigned int pk_bf16(float a, float b) {  // packed RNE pair
    __hip_bfloat162 t = __float22bfloat162_rn(make_float2(a, b));
    unsigned int bits;
    __builtin_memcpy(&bits, &t, 4);
    return bits;
}

// x = hi + lo: hi = truncated bf16, lo = RNE bf16 of remainder -> ~2^-17 |x| residual
__device__ inline void split_bf(float v, unsigned short& h, unsigned short& l) {
    unsigned int u = __float_as_uint(v);
    h = (unsigned short)(u >> 16);
    float hf = __uint_as_float(u & 0xffff0000u);
    l = f2bf(v - hf);
}

// x = hi + mid + lo: ~2^-25 |x| residual
__device__ inline void split3_bf(float v, unsigned short& h, unsigned short& m, unsigned short& l) {
    unsigned int u = __float_as_uint(v);
    h = (unsigned short)(u >> 16);
    float hf = __uint_as_float(u & 0xffff0000u);
    float r1 = v - hf;
    unsigned int u1 = __float_as_uint(r1);
    m = (unsigned short)(u1 >> 16);
    float mf = __uint_as_float(u1 & 0xffff0000u);
    l = f2bf(r1 - mf);
}

__device__ inline unsigned long long pack4(const unsigned short* s) {
    return (unsigned long long)s[0] | ((unsigned long long)s[1] << 16)
         | ((unsigned long long)s[2] << 32) | ((unsigned long long)s[3] << 48);
}

// One unit of weight pre-splitting; 98304 units over gram_partial's 256 blocks x 384 lanes.
// Regions: 0=wq(triple) 1=wk(triple) 2=wo(double) 3=wv^T(double).
__device__ inline void split_unit(int u, const float* wq, const float* wk,
                                  const float* wv, const float* wo, float* ws) {
    int region = u / 24576;
    int r = u - region * 24576;
    if (region < 3) {
        const float* src = (region == 0) ? wq : (region == 1) ? wk : wo;
        int i = r * 4;
        float4 v = *(const float4*)(src + i);
        if (region < 2) {
            unsigned short h[4], m[4], l[4];
            split3_bf(v.x, h[0], m[0], l[0]);
            split3_bf(v.y, h[1], m[1], l[1]);
            split3_bf(v.z, h[2], m[2], l[2]);
            split3_bf(v.w, h[3], m[3], l[3]);
            int base = (region == 0) ? WQH_OFF : WKH_OFF;
            *(unsigned long long*)((unsigned short*)(ws + base) + i)              = pack4(h);
            *(unsigned long long*)((unsigned short*)(ws + base + SPL_FL) + i)     = pack4(m);
            *(unsigned long long*)((unsigned short*)(ws + base + 2 * SPL_FL) + i) = pack4(l);
        } else {
            unsigned short h[4], l[4];
            split_bf(v.x, h[0], l[0]);
            split_bf(v.y, h[1], l[1]);
            split_bf(v.z, h[2], l[2]);
            split_bf(v.w, h[3], l[3]);
            *(unsigned long long*)((unsigned short*)(ws + WOH_OFF) + i) = pack4(h);
            *(unsigned long long*)((unsigned short*)(ws + WOL_OFF) + i) = pack4(l);
        }
    } else {
        int j4 = r / 192;
        int c  = r - j4 * 192;
        int j  = j4 * 4;
        unsigned short h[4], l[4];
#pragma unroll
        for (int jj = 0; jj < 4; ++jj)
            split_bf(wv[(size_t)(j + jj) * C_IN + c], h[jj], l[jj]);
        *(unsigned long long*)((unsigned short*)(ws + WVTH_OFF) + c * 512 + j) = pack4(h);
        *(unsigned long long*)((unsigned short*)(ws + WVTL_OFF) + c * 512 + j) = pack4(l);
    }
}

// ---------------- Gram via split-bf16 MFMA: P[b][slice] = X-slice * X-slice^T ----------------
__global__ __launch_bounds__(512, 2) void gram_partial(const float* __restrict__ x,
                                                       const float* __restrict__ wq,
                                                       const float* __restrict__ wk,
                                                       const float* __restrict__ wv,
                                                       const float* __restrict__ wo,
                                                       float* __restrict__ ws) {
    int b     = blockIdx.y;
    int slice = blockIdx.x;
    int kbase = slice * (GR_CH * GR_BK);

    __shared__ unsigned short Hs[192 * 40];
    __shared__ unsigned short Lo[192 * 40];

    int tid  = threadIdx.x;
    int wave = tid >> 6;
    int lane = tid & 63;
    int rw   = wave & 3;
    int cw   = wave >> 2;
    int lm   = lane & 15, quad = lane >> 4;

    const float* xb = x + (size_t)b * C_IN * S_TOT;

    int lc[3], lkq[3];
#pragma unroll
    for (int q = 0; q < 3; q++) { int id = tid + 512 * q; lc[q] = id >> 3; lkq[q] = id & 7; }

    f32x4 acc[3][6];
#pragma unroll
    for (int mt = 0; mt < 3; mt++)
#pragma unroll
        for (int nt = 0; nt < 6; nt++) acc[mt][nt] = (f32x4){0.f, 0.f, 0.f, 0.f};

    float4 pf[3];
#pragma unroll
    for (int q = 0; q < 3; q++)
        pf[q] = *(const float4*)(xb + (size_t)lc[q] * S_TOT + kbase + lkq[q] * 4);

    if (tid < 384) split_unit((b * NSLICE + slice) * 384 + tid, wq, wk, wv, wo, ws);

    for (int ch = 0; ch < GR_CH; ++ch) {
        __syncthreads();
#pragma unroll
        for (int q = 0; q < 3; q++) {
            unsigned short h[4], l[4];
            split_bf(pf[q].x, h[0], l[0]);
            split_bf(pf[q].y, h[1], l[1]);
            split_bf(pf[q].z, h[2], l[2]);
            split_bf(pf[q].w, h[3], l[3]);
            *(unsigned long long*)&Hs[lc[q] * 40 + lkq[q] * 4] = pack4(h);
            *(unsigned long long*)&Lo[lc[q] * 40 + lkq[q] * 4] = pack4(l);
        }
        __syncthreads();
        if (ch + 1 < GR_CH) {
            int k0 = kbase + (ch + 1) * GR_BK;
#pragma unroll
            for (int q = 0; q < 3; q++)
                pf[q] = *(const float4*)(xb + (size_t)lc[q] * S_TOT + k0 + lkq[q] * 4);
        }

        short8 ah[3], al[3];
#pragma unroll
        for (int mt = 0; mt < 3; mt++) {
            int row = 48 * rw + mt * 16 + lm;
            ah[mt] = *(const short8*)&Hs[row * 40 + quad * 8];
            al[mt] = *(const short8*)&Lo[row * 40 + quad * 8];
        }
#pragma unroll
        for (int nt = 0; nt < 6; nt++) {
            int col = 96 * cw + nt * 16 + lm;
            short8 bh = *(const short8*)&Hs[col * 40 + quad * 8];
            short8 bl = *(const short8*)&Lo[col * 40 + quad * 8];
#pragma unroll
            for (int mt = 0; mt < 3; mt++) {
                acc[mt][nt] = __builtin_amdgcn_mfma_f32_16x16x32_bf16(ah[mt], bh, acc[mt][nt], 0, 0, 0);
                acc[mt][nt] = __builtin_amdgcn_mfma_f32_16x16x32_bf16(ah[mt], bl, acc[mt][nt], 0, 0, 0);
                acc[mt][nt] = __builtin_amdgcn_mfma_f32_16x16x32_bf16(al[mt], bh, acc[mt][nt], 0, 0, 0);
            }
        }
    }

    float* Pb = ws + P_OFF + ((size_t)(b * NSLICE + slice)) * (C_IN * C_IN);
#pragma unroll
    for (int mt = 0; mt < 3; mt++) {
#pragma unroll
        for (int r = 0; r < 4; r++) {
            int row = 48 * rw + mt * 16 + quad * 4 + r;
#pragma unroll
            for (int nt = 0; nt < 6; nt++)
                Pb[row * C_IN + 96 * cw + nt * 16 + lm] = acc[mt][nt][r];
        }
    }
}

// ---------------- Gram reduce: single pass, emits triple-split G ----------------
__global__ __launch_bounds__(64) void gram_reduce(float* __restrict__ ws) {
    int b = blockIdx.y;
    int idx4 = (blockIdx.x * 64 + threadIdx.x) * 4;
    const float* Pb = ws + P_OFF + (size_t)(b * NSLICE) * GEL + idx4;
    float4 acc = {0.f, 0.f, 0.f, 0.f};
#pragma unroll 8
    for (int s = 0; s < NSLICE; ++s) {
        float4 v = *(const float4*)(Pb + (size_t)s * GEL);
        acc.x += v.x; acc.y += v.y; acc.z += v.z; acc.w += v.w;
    }
    unsigned short h[4], m[4], l[4];
    split3_bf(acc.x, h[0], m[0], l[0]);
    split3_bf(acc.y, h[1], m[1], l[1]);
    split3_bf(acc.z, h[2], m[2], l[2]);
    split3_bf(acc.w, h[3], m[3], l[3]);
    *(unsigned long long*)((unsigned short*)(ws + GH_OFF) + (size_t)b * GEL + idx4) = pack4(h);
    *(unsigned long long*)((unsigned short*)(ws + GM_OFF) + (size_t)b * GEL + idx4) = pack4(m);
    *(unsigned long long*)((unsigned short*)(ws + GL_OFF) + (size_t)b * GEL + idx4) = pack4(l);
}

// ---------------- Qt = Wq * G (512x192), 6-term triple MFMA, triple-split out ----------------
// grid (NB, NH, 2): 32 blocks, 256 thr. Batched B-load arrays -> 21 loads in flight per chunk.
__global__ __launch_bounds__(256) void proj_kernel(float* __restrict__ ws) {
    int b  = blockIdx.x;
    int h  = blockIdx.y;
    int cg = blockIdx.z;
    int tid = threadIdx.x, wave = tid >> 6, lane = tid & 63;
    int lm = lane & 15, quad = lane >> 4;

    const unsigned short* AH = (const unsigned short*)(ws + WQH_OFF);
    const unsigned short* AM = (const unsigned short*)(ws + WQM_OFF);
    const unsigned short* AL = (const unsigned short*)(ws + WQL_OFF);
    const unsigned short* GH = (const unsigned short*)(ws + GH_OFF) + (size_t)b * GEL;
    const unsigned short* GM = (const unsigned short*)(ws + GM_OFF) + (size_t)b * GEL;
    const unsigned short* GL = (const unsigned short*)(ws + GL_OFF) + (size_t)b * GEL;

    int arow = (h * 64 + wave * 16 + lm) * C_IN;

    f32x4 acc[6];
#pragma unroll
    for (int ct = 0; ct < 6; ++ct) acc[ct] = (f32x4){0.f, 0.f, 0.f, 0.f};

#pragma unroll
    for (int ch = 0; ch < 6; ++ch) {
        int k0 = ch * 32 + quad * 8;
        short8 aH = *(const short8*)(AH + arow + k0);
        short8 aM = *(const short8*)(AM + arow + k0);
        short8 aL = *(const short8*)(AL + arow + k0);
        short8 bH[6], bM[6], bL[6];
#pragma unroll
        for (int ct = 0; ct < 6; ++ct) {
            int gr = (cg * 96 + ct * 16 + lm) * C_IN + k0;
            bH[ct] = *(const short8*)(GH + gr);
            bM[ct] = *(const short8*)(GM + gr);
            bL[ct] = *(const short8*)(GL + gr);
        }
#pragma unroll
        for (int ct = 0; ct < 6; ++ct) {
            acc[ct] = __builtin_amdgcn_mfma_f32_16x16x32_bf16(aH, bH[ct], acc[ct], 0, 0, 0);
            acc[ct] = __builtin_amdgcn_mfma_f32_16x16x32_bf16(aH, bM[ct], acc[ct], 0, 0, 0);
            acc[ct] = __builtin_amdgcn_mfma_f32_16x16x32_bf16(aM, bH[ct], acc[ct], 0, 0, 0);
            acc[ct] = __builtin_amdgcn_mfma_f32_16x16x32_bf16(aH, bL[ct], acc[ct], 0, 0, 0);
            acc[ct] = __builtin_amdgcn_mfma_f32_16x16x32_bf16(aM, bM[ct], acc[ct], 0, 0, 0);
            acc[ct] = __builtin_amdgcn_mfma_f32_16x16x32_bf16(aL, bH[ct], acc[ct], 0, 0, 0);
        }
    }

    unsigned short* QH = (unsigned short*)(ws + QTH_OFF) + (size_t)b * PT_EL;
    unsigned short* QM = (unsigned short*)(ws + QTM_OFF) + (size_t)b * PT_EL;
    unsigned short* QL = (unsigned short*)(ws + QTL_OFF) + (size_t)b * PT_EL;
#pragma unroll
    for (int ct = 0; ct < 6; ++ct)
#pragma unroll
        for (int r = 0; r < 4; ++r) {
            int row = h * 64 + wave * 16 + quad * 4 + r;
            int col = cg * 96 + ct * 16 + lm;
            unsigned short hh, mm, ll;
            split3_bf(acc[ct][r], hh, mm, ll);
            QH[row * C_IN + col] = hh;
            QM[row * C_IN + col] = mm;
            QL[row * C_IN + col] = ll;
        }
}

// ---------------- attn: sim = Qt_h*Wk_h^T -> softmax -> Z_h = Wo_h*attn ----------------
// grid (NB, NH), 256 thr. sim 6-term triple x triple; Z double-split.
__global__ __launch_bounds__(256) void attn_kernel(float* __restrict__ ws) {
    int b = blockIdx.x, h = blockIdx.y;
    int tid  = threadIdx.x;
    int wave = tid >> 6;
    int lane = tid & 63;
    int lm = lane & 15, quad = lane >> 4;

    __shared__ float At[64 * 68];   // attn^T [j][i]

    const unsigned short* QH = (const unsigned short*)(ws + QTH_OFF) + (size_t)b * PT_EL;
    const unsigned short* QM = (const unsigned short*)(ws + QTM_OFF) + (size_t)b * PT_EL;
    const unsigned short* QL = (const unsigned short*)(ws + QTL_OFF) + (size_t)b * PT_EL;
    const unsigned short* KH = (const unsigned short*)(ws + WKH_OFF);
    const unsigned short* KM = (const unsigned short*)(ws + WKM_OFF);
    const unsigned short* KL = (const unsigned short*)(ws + WKL_OFF);
    const unsigned short* WOHp = (const unsigned short*)(ws + WOH_OFF);
    const unsigned short* WOLp = (const unsigned short*)(ws + WOL_OFF);

    // ---- sim (64x64, K=192) ----
    f32x4 sacc[4];
#pragma unroll
    for (int ct = 0; ct < 4; ++ct) sacc[ct] = (f32x4){0.f, 0.f, 0.f, 0.f};

    int ar = (h * 64 + wave * 16 + lm) * C_IN;
#pragma unroll
    for (int ch = 0; ch < 6; ++ch) {
        int k0 = ch * 32 + quad * 8;
        short8 aH = *(const short8*)(QH + ar + k0);
        short8 aM = *(const short8*)(QM + ar + k0);
        short8 aL = *(const short8*)(QL + ar + k0);
        short8 bH[4], bM[4], bL[4];
#pragma unroll
        for (int ct = 0; ct < 4; ++ct) {
            int kr = (h * 64 + ct * 16 + lm) * C_IN + k0;
            bH[ct] = *(const short8*)(KH + kr);
            bM[ct] = *(const short8*)(KM + kr);
            bL[ct] = *(const short8*)(KL + kr);
        }
#pragma unroll
        for (int ct = 0; ct < 4; ++ct) {
            sacc[ct] = __builtin_amdgcn_mfma_f32_16x16x32_bf16(aH, bH[ct], sacc[ct], 0, 0, 0);
            sacc[ct] = __builtin_amdgcn_mfma_f32_16x16x32_bf16(aH, bM[ct], sacc[ct], 0, 0, 0);
            sacc[ct] = __builtin_amdgcn_mfma_f32_16x16x32_bf16(aM, bH[ct], sacc[ct], 0, 0, 0);
            sacc[ct] = __builtin_amdgcn_mfma_f32_16x16x32_bf16(aH, bL[ct], sacc[ct], 0, 0, 0);
            sacc[ct] = __builtin_amdgcn_mfma_f32_16x16x32_bf16(aM, bM[ct], sacc[ct], 0, 0, 0);
            sacc[ct] = __builtin_amdgcn_mfma_f32_16x16x32_bf16(aL, bH[ct], sacc[ct], 0, 0, 0);
        }
    }

    // ---- softmax over j, store attn^T [j][i] ----
#pragma unroll
    for (int r = 0; r < 4; ++r) {
        float s0 = sacc[0][r] * ATT_SCALE;
        float s1 = sacc[1][r] * ATT_SCALE;
        float s2 = sacc[2][r] * ATT_SCALE;
        float s3 = sacc[3][r] * ATT_SCALE;
        float mx = fmaxf(fmaxf(s0, s1), fmaxf(s2, s3));
        mx = fmaxf(mx, __shfl_xor(mx, 1));
        mx = fmaxf(mx, __shfl_xor(mx, 2));
        mx = fmaxf(mx, __shfl_xor(mx, 4));
        mx = fmaxf(mx, __shfl_xor(mx, 8));
        float e0 = __expf(s0 - mx), e1 = __expf(s1 - mx);
        float e2 = __expf(s2 - mx), e3 = __expf(s3 - mx);
        float sum = (e0 + e1) + (e2 + e3);
        sum += __shfl_xor(sum, 1);
        sum += __shfl_xor(sum, 2);
        sum += __shfl_xor(sum, 4);
        sum += __shfl_xor(sum, 8);
        float inv = 1.0f / sum;
        int i = wave * 16 + quad * 4 + r;
        At[lm * 68 + i]        = e0 * inv;
        At[(16 + lm) * 68 + i] = e1 * inv;
        At[(32 + lm) * 68 + i] = e2 * inv;
        At[(48 + lm) * 68 + i] = e3 * inv;
    }
    __syncthreads();

    // ---- Z_h = Wo[:, 64h:64h+64] * attn (192x64, K=64), double-split ----
    f32x4 zacc[3][4];
#pragma unroll
    for (int mt = 0; mt < 3; ++mt)
#pragma unroll
        for (int ct = 0; ct < 4; ++ct) zacc[mt][ct] = (f32x4){0.f, 0.f, 0.f, 0.f};

#pragma unroll
    for (int ch = 0; ch < 2; ++ch) {
        int k0 = ch * 32 + quad * 8;
        short8 bH[4], bL[4];
#pragma unroll
        for (int ct = 0; ct < 4; ++ct) {
            float av[8];
            *(float4*)&av[0] = *(const float4*)&At[(ct * 16 + lm) * 68 + k0];
            *(float4*)&av[4] = *(const float4*)&At[(ct * 16 + lm) * 68 + k0 + 4];
#pragma unroll
            for (int j = 0; j < 8; ++j) {
                unsigned short hh, ll;
                split_bf(av[j], hh, ll);
                bH[ct][j] = (short)hh; bL[ct][j] = (short)ll;
            }
        }
#pragma unroll
        for (int mt = 0; mt < 3; ++mt) {
            int orow = (wave * 48 + mt * 16 + lm) * 512 + h * 64 + k0;
            short8 aH = *(const short8*)(WOHp + orow);
            short8 aL = *(const short8*)(WOLp + orow);
#pragma unroll
            for (int ct = 0; ct < 4; ++ct) {
                zacc[mt][ct] = __builtin_amdgcn_mfma_f32_16x16x32_bf16(aH, bH[ct], zacc[mt][ct], 0, 0, 0);
                zacc[mt][ct] = __builtin_amdgcn_mfma_f32_16x16x32_bf16(aH, bL[ct], zacc[mt][ct], 0, 0, 0);
                zacc[mt][ct] = __builtin_amdgcn_mfma_f32_16x16x32_bf16(aL, bH[ct], zacc[mt][ct], 0, 0, 0);
            }
        }
    }

    unsigned short* ZHb = (unsigned short*)(ws + ZH_OFF) + (size_t)b * ZEL;
    unsigned short* ZLb = (unsigned short*)(ws + ZL_OFF) + (size_t)b * ZEL;
#pragma unroll
    for (int mt = 0; mt < 3; ++mt)
#pragma unroll
        for (int r = 0; r < 4; ++r) {
            int o = wave * 48 + mt * 16 + quad * 4 + r;
#pragma unroll
            for (int ct = 0; ct < 4; ++ct) {
                unsigned short hh, ll;
                split_bf(zacc[mt][ct][r], hh, ll);
                int idx = o * 512 + h * 64 + ct * 16 + lm;
                ZHb[idx] = hh;
                ZLb[idx] = ll;
            }
        }
}

// ---------------- W = Z * Wv^T (192x192, K=512), register double-buffered ----------------
#define WMIX_LOAD(CH, AH, AL, BH, BL)                                         \
    do {                                                                      \
        int k0_ = (CH) * 32 + quad * 8;                                       \
        for (int mt_ = 0; mt_ < 3; ++mt_) {                                   \
            int o_ = (rw * 48 + mt_ * 16 + lm) * 512 + k0_;                   \
            AH[mt_] = *(const short8*)(ZHb + o_);                             \
            AL[mt_] = *(const short8*)(ZLb + o_);                             \
        }                                                                     \
        for (int ct_ = 0; ct_ < 3; ++ct_) {                                   \
            int c_ = (half * 96 + cw * 48 + ct_ * 16 + lm) * 512 + k0_;       \
            BH[ct_] = *(const short8*)(VTH + c_);                             \
            BL[ct_] = *(const short8*)(VTL + c_);                             \
        }                                                                     \
    } while (0)

#define WMIX_MFMA(AH, AL, BH, BL)                                                               \
    do {                                                                                        \
        for (int ct_ = 0; ct_ < 3; ++ct_)                                                       \
            for (int mt_ = 0; mt_ < 3; ++mt_) {                                                 \
                acc[mt_][ct_] = __builtin_amdgcn_mfma_f32_16x16x32_bf16(AH[mt_], BH[ct_], acc[mt_][ct_], 0, 0, 0); \
                acc[mt_][ct_] = __builtin_amdgcn_mfma_f32_16x16x32_bf16(AH[mt_], BL[ct_], acc[mt_][ct_], 0, 0, 0); \
                acc[mt_][ct_] = __builtin_amdgcn_mfma_f32_16x16x32_bf16(AL[mt_], BH[ct_], acc[mt_][ct_], 0, 0, 0); \
            }                                                                                   \
    } while (0)

__global__ __launch_bounds__(512) void wmix_kernel(float* __restrict__ ws) {
    int b = blockIdx.x, half = blockIdx.y;
    int tid  = threadIdx.x;
    int wave = tid >> 6, lane = tid & 63;
    int lm = lane & 15, quad = lane >> 4;
    int rw = wave & 3, cw = wave >> 2;

    const unsigned short* ZHb = (const unsigned short*)(ws + ZH_OFF) + (size_t)b * ZEL;
    const unsigned short* ZLb = (const unsigned short*)(ws + ZL_OFF) + (size_t)b * ZEL;
    const unsigned short* VTH = (const unsigned short*)(ws + WVTH_OFF);
    const unsigned short* VTL = (const unsigned short*)(ws + WVTL_OFF);

    f32x4 acc[3][3];
#pragma unroll
    for (int mt = 0; mt < 3; ++mt)
#pragma unroll
        for (int ct = 0; ct < 3; ++ct) acc[mt][ct] = (f32x4){0.f, 0.f, 0.f, 0.f};

    short8 aH0[3], aL0[3], bH0[3], bL0[3];
    short8 aH1[3], aL1[3], bH1[3], bL1[3];
    WMIX_LOAD(0, aH0, aL0, bH0, bL0);
#pragma unroll
    for (int ch = 0; ch < 16; ch += 2) {
        WMIX_LOAD(ch + 1, aH1, aL1, bH1, bL1);
        WMIX_MFMA(aH0, aL0, bH0, bL0);
        if (ch + 2 < 16) WMIX_LOAD(ch + 2, aH0, aL0, bH0, bL0);
        WMIX_MFMA(aH1, aL1, bH1, bL1);
    }

    unsigned short* Wb = (unsigned short*)(ws + WBF_OFF) + (size_t)b * C_IN * C_IN;
#pragma unroll
    for (int mt = 0; mt < 3; ++mt)
#pragma unroll
        for (int r = 0; r < 4; ++r) {
            int m = rw * 48 + mt * 16 + quad * 4 + r;
#pragma unroll
            for (int ct = 0; ct < 3; ++ct)
                Wb[m * C_IN + half * 96 + cw * 48 + ct * 16 + lm] = f2bf(acc[mt][ct][r]);
        }
}

// ---------------- Gram fallback (fp32 atomic; used only if ws too small) ----------------
__global__ __launch_bounds__(512, 2) void gram_atomic(const float* __restrict__ x,
                                                      float* __restrict__ G) {
    int b     = blockIdx.y;
    int kbase = blockIdx.x * (GR_CH * GR_BK);

    __shared__ float Ls[GR_BK][196];

    int tid = threadIdx.x;
    int tx  = tid & 15;
    int tyy = tid >> 4;

    const float* xb = x + (size_t)b * C_IN * S_TOT;

    int lc[3], lkq[3];
#pragma unroll
    for (int q = 0; q < 3; q++) { int id = tid + 512 * q; lc[q] = id >> 3; lkq[q] = id & 7; }

    float acc[6][12] = {};
    float4 pf[3];

#pragma unroll
    for (int q = 0; q < 3; q++)
        pf[q] = *(const float4*)(xb + (size_t)lc[q] * S_TOT + kbase + lkq[q] * 4);

    for (int ch = 0; ch < GR_CH; ++ch) {
        __syncthreads();
#pragma unroll
        for (int q = 0; q < 3; q++) {
            Ls[lkq[q] * 4 + 0][lc[q]] = pf[q].x;
            Ls[lkq[q] * 4 + 1][lc[q]] = pf[q].y;
            Ls[lkq[q] * 4 + 2][lc[q]] = pf[q].z;
            Ls[lkq[q] * 4 + 3][lc[q]] = pf[q].w;
        }
        __syncthreads();
        if (ch + 1 < GR_CH) {
            int k0 = kbase + (ch + 1) * GR_BK;
#pragma unroll
            for (int q = 0; q < 3; q++)
                pf[q] = *(const float4*)(xb + (size_t)lc[q] * S_TOT + k0 + lkq[q] * 4);
        }
#pragma unroll
        for (int kk = 0; kk < GR_BK; ++kk) {
            float a[6], bb[12];
#pragma unroll
            for (int rr = 0; rr < 6; ++rr)  a[rr] = Ls[kk][tyy + 32 * rr];
#pragma unroll
            for (int cc = 0; cc < 12; ++cc) bb[cc] = Ls[kk][tx + 16 * cc];
#pragma unroll
            for (int rr = 0; rr < 6; ++rr)
#pragma unroll
                for (int cc = 0; cc < 12; ++cc)
                    acc[rr][cc] = fmaf(a[rr], bb[cc], acc[rr][cc]);
        }
    }

    float* Gb = G + b * C_IN * C_IN;
#pragma unroll
    for (int rr = 0; rr < 6; ++rr)
#pragma unroll
        for (int cc = 0; cc < 12; ++cc)
            atomicAdd(&Gb[(tyy + 32 * rr) * C_IN + tx + 16 * cc], acc[rr][cc]);
}

// ---------------- generic 64x64-tile GEMM (fp32 out; fallback path) ----------------
__global__ __launch_bounds__(256) void gemm64_kernel(const float* __restrict__ A,
                                                     const float* __restrict__ B,
                                                     float* __restrict__ C,
                                                     int K, int N,
                                                     long aStride, long bStride, long cStride) {
    int mi0 = blockIdx.x * 64;
    int nj0 = blockIdx.y * 64;
    int b   = blockIdx.z;

    __shared__ float As[16][68];
    __shared__ float Bs[16][68];

    int tid = threadIdx.x;
    int tx = tid & 15, ty = tid >> 4;
    int lrow = tid >> 2, lk = (tid & 3) * 4;
    int ldk = tid >> 4, ldn = (tid & 15) * 4;

    const float* Ab = A + b * aStride;
    const float* Bb = B + b * bStride;

    float acc[4][4] = {};

    for (int k0 = 0; k0 < K; k0 += 16) {
        float4 av = *(const float4*)(Ab + (size_t)(mi0 + lrow) * K + k0 + lk);
        float4 bv = *(const float4*)(Bb + (size_t)(k0 + ldk) * N + nj0 + ldn);
        __syncthreads();
        As[lk + 0][lrow] = av.x; As[lk + 1][lrow] = av.y;
        As[lk + 2][lrow] = av.z; As[lk + 3][lrow] = av.w;
        *(float4*)&Bs[ldk][ldn] = bv;
        __syncthreads();
#pragma unroll
        for (int kk = 0; kk < 16; kk++) {
            float4 a = *(const float4*)&As[kk][ty * 4];
            float4 bb = *(const float4*)&Bs[kk][tx * 4];
            acc[0][0] += a.x * bb.x; acc[0][1] += a.x * bb.y; acc[0][2] += a.x * bb.z; acc[0][3] += a.x * bb.w;
            acc[1][0] += a.y * bb.x; acc[1][1] += a.y * bb.y; acc[1][2] += a.y * bb.z; acc[1][3] += a.y * bb.w;
            acc[2][0] += a.z * bb.x; acc[2][1] += a.z * bb.y; acc[2][2] += a.z * bb.z; acc[2][3] += a.z * bb.w;
            acc[3][0] += a.w * bb.x; acc[3][1] += a.w * bb.y; acc[3][2] += a.w * bb.z; acc[3][3] += a.w * bb.w;
        }
    }

    float* Cb = C + b * cStride;
#pragma unroll
    for (int r = 0; r < 4; r++) {
        float4 v = { acc[r][0], acc[r][1], acc[r][2], acc[r][3] };
        *(float4*)(Cb + (size_t)(mi0 + ty * 4 + r) * N + nj0 + tx * 4) = v;
    }
}

// ---------------- same GEMM, bf16 packed output (fallback path) ----------------
__global__ __launch_bounds__(256) void gemm64bf_kernel(const float* __restrict__ A,
                                                       const float* __restrict__ B,
                                                       unsigned short* __restrict__ C,
                                                       int K, int N,
                                                       long aStride, long bStride, long cStride) {
    int mi0 = blockIdx.x * 64;
    int nj0 = blockIdx.y * 64;
    int b   = blockIdx.z;

    __shared__ float As[16][68];
    __shared__ float Bs[16][68];

    int tid = threadIdx.x;
    int tx = tid & 15, ty = tid >> 4;
    int lrow = tid >> 2, lk = (tid & 3) * 4;
    int ldk = tid >> 4, ldn = (tid & 15) * 4;

    const float* Ab = A + b * aStride;
    const float* Bb = B + b * bStride;

    float acc[4][4] = {};

    for (int k0 = 0; k0 < K; k0 += 16) {
        float4 av = *(const float4*)(Ab + (size_t)(mi0 + lrow) * K + k0 + lk);
        float4 bv = *(const float4*)(Bb + (size_t)(k0 + ldk) * N + nj0 + ldn);
        __syncthreads();
        As[lk + 0][lrow] = av.x; As[lk + 1][lrow] = av.y;
        As[lk + 2][lrow] = av.z; As[lk + 3][lrow] = av.w;
        *(float4*)&Bs[ldk][ldn] = bv;
        __syncthreads();
#pragma unroll
        for (int kk = 0; kk < 16; kk++) {
            float4 a = *(const float4*)&As[kk][ty * 4];
            float4 bb = *(const float4*)&Bs[kk][tx * 4];
            acc[0][0] += a.x * bb.x; acc[0][1] += a.x * bb.y; acc[0][2] += a.x * bb.z; acc[0][3] += a.x * bb.w;
            acc[1][0] += a.y * bb.x; acc[1][1] += a.y * bb.y; acc[1][2] += a.y * bb.z; acc[1][3] += a.y * bb.w;
            acc[2][0] += a.z * bb.x; acc[2][1] += a.z * bb.y; acc[2][2] += a.z * bb.z; acc[2][3] += a.z * bb.w;
            acc[3][0] += a.w * bb.x; acc[3][1] += a.w * bb.y; acc[3][2] += a.w * bb.z; acc[3][3] += a.w * bb.w;
        }
    }

    unsigned short* Cb = C + b * cStride;
#pragma unroll
    for (int r = 0; r < 4; r++) {
        union { unsigned long long q; unsigned int u[2]; } pk;
        pk.u[0] = pk_bf16(acc[r][0], acc[r][1]);
        pk.u[1] = pk_bf16(acc[r][2], acc[r][3]);
        *(unsigned long long*)&Cb[(size_t)(mi0 + ty * 4 + r) * N + nj0 + tx * 4] = pk.q;
    }
}

// ---------------- fallback fused sim/softmax/M ----------------
__global__ __launch_bounds__(256) void simsoftm_kernel(const float* __restrict__ T,
                                                       const float* __restrict__ wk,
                                                       const float* __restrict__ wv,
                                                       float* __restrict__ M) {
    int b = blockIdx.x, h = blockIdx.y;

    __shared__ float As[16][68];
    __shared__ float Bs[16][68];
    __shared__ float At[64][68];

    int tid = threadIdx.x;
    int tx = tid & 15, ty = tid >> 4;
    int ldk = tid >> 4, ldn = (tid & 15) * 4;
    int lrow = tid >> 2, lk = (tid & 3) * 4;

    const float* Th  = T + (size_t)b * 512 * C_IN + (size_t)(h * 64) * C_IN;
    const float* wkh = wk + (size_t)(h * 64) * C_IN;
    const float* wvh = wv + (size_t)(h * 64) * C_IN;

    float acc[4][4] = {};
    for (int k0 = 0; k0 < C_IN; k0 += 16) {
        float4 av = *(const float4*)(Th  + (size_t)lrow * C_IN + k0 + lk);
        float4 bv = *(const float4*)(wkh + (size_t)lrow * C_IN + k0 + lk);
        __syncthreads();
        As[lk + 0][lrow] = av.x; As[lk + 1][lrow] = av.y;
        As[lk + 2][lrow] = av.z; As[lk + 3][lrow] = av.w;
        Bs[lk + 0][lrow] = bv.x; Bs[lk + 1][lrow] = bv.y;
        Bs[lk + 2][lrow] = bv.z; Bs[lk + 3][lrow] = bv.w;
        __syncthreads();
#pragma unroll
        for (int kk = 0; kk < 16; kk++) {
            float4 a = *(const float4*)&As[kk][ty * 4];
            float4 bb = *(const float4*)&Bs[kk][tx * 4];
            acc[0][0] += a.x * bb.x; acc[0][1] += a.x * bb.y; acc[0][2] += a.x * bb.z; acc[0][3] += a.x * bb.w;
            acc[1][0] += a.y * bb.x; acc[1][1] += a.y * bb.y; acc[1][2] += a.y * bb.z; acc[1][3] += a.y * bb.w;
            acc[2][0] += a.z * bb.x; acc[2][1] += a.z * bb.y; acc[2][2] += a.z * bb.z; acc[2][3] += a.z * bb.w;
            acc[3][0] += a.w * bb.x; acc[3][1] += a.w * bb.y; acc[3][2] += a.w * bb.z; acc[3][3] += a.w * bb.w;
        }
    }

#pragma unroll
    for (int r = 0; r < 4; r++) {
        float s0 = acc[r][0] * ATT_SCALE, s1 = acc[r][1] * ATT_SCALE;
        float s2 = acc[r][2] * ATT_SCALE, s3 = acc[r][3] * ATT_SCALE;
        float mx = fmaxf(fmaxf(s0, s1), fmaxf(s2, s3));
        mx = fmaxf(mx, __shfl_xor(mx, 1));
        mx = fmaxf(mx, __shfl_xor(mx, 2));
        mx = fmaxf(mx, __shfl_xor(mx, 4));
        mx = fmaxf(mx, __shfl_xor(mx, 8));
        float e0 = __expf(s0 - mx), e1 = __expf(s1 - mx);
        float e2 = __expf(s2 - mx), e3 = __expf(s3 - mx);
        float sum = (e0 + e1) + (e2 + e3);
        sum += __shfl_xor(sum, 1);
        sum += __shfl_xor(sum, 2);
        sum += __shfl_xor(sum, 4);
        sum += __shfl_xor(sum, 8);
        float inv = 1.0f / sum;
        At[tx * 4 + 0][ty * 4 + r] = e0 * inv;
        At[tx * 4 + 1][ty * 4 + r] = e1 * inv;
        At[tx * 4 + 2][ty * 4 + r] = e2 * inv;
        At[tx * 4 + 3][ty * 4 + r] = e3 * inv;
    }

    float* Mb = M + (size_t)b * 512 * C_IN + (size_t)(h * 64) * C_IN;
    for (int nj = 0; nj < C_IN; nj += 64) {
        float acc2[4][4] = {};
        for (int j0 = 0; j0 < 64; j0 += 16) {
            float4 bv = *(const float4*)(wvh + (size_t)(j0 + ldk) * C_IN + nj + ldn);
            __syncthreads();
            *(float4*)&Bs[ldk][ldn] = bv;
            __syncthreads();
#pragma unroll
            for (int kk = 0; kk < 16; kk++) {
                float4 a = *(const float4*)&At[j0 + kk][ty * 4];
                float4 bb = *(const float4*)&Bs[kk][tx * 4];
                acc2[0][0] += a.x * bb.x; acc2[0][1] += a.x * bb.y; acc2[0][2] += a.x * bb.z; acc2[0][3] += a.x * bb.w;
                acc2[1][0] += a.y * bb.x; acc2[1][1] += a.y * bb.y; acc2[1][2] += a.y * bb.z; acc2[1][3] += a.y * bb.w;
                acc2[2][0] += a.z * bb.x; acc2[2][1] += a.z * bb.y; acc2[2][2] += a.z * bb.z; acc2[2][3] += a.z * bb.w;
                acc2[3][0] += a.w * bb.x; acc2[3][1] += a.w * bb.y; acc2[3][2] += a.w * bb.z; acc2[3][3] += a.w * bb.w;
            }
        }
#pragma unroll
        for (int r = 0; r < 4; r++) {
            float4 v = { acc2[r][0], acc2[r][1], acc2[r][2], acc2[r][3] };
            *(float4*)(Mb + (size_t)(ty * 4 + r) * C_IN + nj + tx * 4) = v;
        }
    }
}

// ---------------- out = W*x + bo, bf16 MFMA. grid (256, NB), block 256 (4 waves) ----------------
__global__ __launch_bounds__(256) void final_kernel(const float* __restrict__ x,
                                                    const unsigned short* __restrict__ Wbf,
                                                    const float* __restrict__ bo,
                                                    float* __restrict__ out) {
    int n0 = blockIdx.x * 128;
    int b  = blockIdx.y;

    __shared__ unsigned short Xs[128 * 40];

    int tid  = threadIdx.x;
    int wave = tid >> 6;
    int lane = tid & 63;
    int wm   = (wave & 1) * 96;
    int wn   = (wave >> 1) * 64;
    int lm   = lane & 15, quad = lane >> 4;

    int sn  = tid & 127;
    int skh = (tid >> 7) * 16;

    const float* xsrc = x + (size_t)b * C_IN * S_TOT + n0 + sn;
    const unsigned short* Wb = Wbf + b * C_IN * C_IN;

    f32x4 acc[6][4];
#pragma unroll
    for (int mt = 0; mt < 6; mt++)
#pragma unroll
        for (int nt = 0; nt < 4; nt++) acc[mt][nt] = (f32x4){0.f, 0.f, 0.f, 0.f};

    float pf[16];
#pragma unroll
    for (int j = 0; j < 16; j++) pf[j] = xsrc[(size_t)(skh + j) * S_TOT];

    for (int kc = 0; kc < 6; ++kc) {
        int k0 = kc * 32;
        __syncthreads();
        {
            union { uint4 q; unsigned int u[4]; } pk0, pk1;
#pragma unroll
            for (int j = 0; j < 4; j++) {
                pk0.u[j] = pk_bf16(pf[2 * j],     pf[2 * j + 1]);
                pk1.u[j] = pk_bf16(pf[8 + 2 * j], pf[8 + 2 * j + 1]);
            }
            *(uint4*)&Xs[sn * 40 + skh + 0] = pk0.q;
            *(uint4*)&Xs[sn * 40 + skh + 8] = pk1.q;
        }
        __syncthreads();
        if (kc + 1 < 6) {
            int kn = k0 + 32;
#pragma unroll
            for (int j = 0; j < 16; j++) pf[j] = xsrc[(size_t)(kn + skh + j) * S_TOT];
        }

        short8 afr[6];
#pragma unroll
        for (int mt = 0; mt < 6; mt++)
            afr[mt] = *(const short8*)(Wb + (size_t)(wm + mt * 16 + lm) * C_IN + k0 + quad * 8);
#pragma unroll
        for (int nt = 0; nt < 4; nt++) {
            short8 bfr = *(const short8*)&Xs[(wn + nt * 16 + lm) * 40 + quad * 8];
#pragma unroll
            for (int mt = 0; mt < 6; mt++)
                acc[mt][nt] = __builtin_amdgcn_mfma_f32_16x16x32_bf16(afr[mt], bfr, acc[mt][nt], 0, 0, 0);
        }
    }

#pragma unroll
    for (int mt = 0; mt < 6; mt++) {
#pragma unroll
        for (int r = 0; r < 4; r++) {
            int m = wm + mt * 16 + quad * 4 + r;
            float bias = bo[m];
            float* op = out + ((size_t)b * C_IN + m) * S_TOT + n0;
#pragma unroll
            for (int nt = 0; nt < 4; nt++)
                op[wn + nt * 16 + lm] = acc[mt][nt][r] + bias;
        }
    }
}

extern "C" void kernel_launch(void* const* d_in, const int* in_sizes, int n_in,
                              void* d_out, int out_size, void* d_ws, size_t ws_size,
                              hipStream_t stream) {
    const float* x  = (const float*)d_in[0];
    const float* wq = (const float*)d_in[1];
    const float* wk = (const float*)d_in[2];
    const float* wv = (const float*)d_in[3];
    const float* wo = (const float*)d_in[4];
    const float* bo = (const float*)d_in[5];
    float* out = (float*)d_out;
    float* ws  = (float*)d_ws;

    unsigned short* gWbf = (unsigned short*)(ws + WBF_OFF);

    bool bigws = ws_size >= (size_t)WS_END * sizeof(float);
    if (bigws) {
        // 6 dispatches: gram(+weight split) -> reduce(+G split) -> Qt proj -> attn -> W-mix -> final
        gram_partial<<<dim3(NSLICE, NB), 512, 0, stream>>>(x, wq, wk, wv, wo, ws);
        gram_reduce<<<dim3(144, NB), 64, 0, stream>>>(ws);
        proj_kernel<<<dim3(NB, NH, 2), 256, 0, stream>>>(ws);
        attn_kernel<<<dim3(NB, NH), 256, 0, stream>>>(ws);
        wmix_kernel<<<dim3(NB, 2), 512, 0, stream>>>(ws);
        final_kernel<<<dim3(256, NB), 256, 0, stream>>>(x, gWbf, bo, out);
    } else {
        // fallback: original proven chain
        float* gG = ws + G_OFF;
        float* gT = ws + T_OFF;
        float* gM = ws + M_OFF;
        hipMemsetAsync(gG, 0, G_SZ * sizeof(float), stream);
        gram_atomic<<<dim3(NSLICE, NB), 512, 0, stream>>>(x, gG);
        gemm64_kernel<<<dim3(8, 3, NB), 256, 0, stream>>>(
            wq, gG, gT, C_IN, C_IN, 0L, (long)(C_IN * C_IN), (long)(512 * C_IN));
        simsoftm_kernel<<<dim3(NB, NH), 256, 0, stream>>>(gT, wk, wv, gM);
        gemm64bf_kernel<<<dim3(3, 3, NB), 256, 0, stream>>>(
            wo, gM, gWbf, 512, C_IN, 0L, (long)(512 * C_IN), (long)(C_IN * C_IN));
        final_kernel<<<dim3(256, NB), 256, 0, stream>>>(x, gWbf, bo, out);
    }
}